// Round 22
// baseline (56.058 us; speedup 1.0000x reference)
//
#include <hip/hip_runtime.h>

typedef __attribute__((ext_vector_type(4))) float f32x4;
typedef __attribute__((ext_vector_type(8))) short bf16x8;

constexpr int NH = 8, D = 128, DK = 16, B = 4, N = 2048;
constexpr int KTILE = 128;
constexpr int NTILES = N / KTILE;       // 16 key-tiles of 128
constexpr int TILE_SHORTS = 6144;       // 12288 B: 8192 B Khl frag + 4096 B Vt swz
constexpr float QSCALE = 0.36067376022224085f;   // 0.25 * log2(e)

__device__ __forceinline__ unsigned short f2bf(float f) {
    union { float f; unsigned u; } v; v.f = f;
    return (unsigned short)((v.u + 0x7fffu + ((v.u >> 16) & 1u)) >> 16);
}
__device__ __forceinline__ float bf2f(unsigned short h) {
    union { unsigned u; float f; } v; v.u = ((unsigned)h) << 16; return v.f;
}
__device__ __forceinline__ unsigned pack2(float a, float b) {   // bf16 trunc pair
    union { float f; unsigned u; } x, y; x.f = a; y.f = b;
    return (x.u >> 16) | (y.u & 0xFFFF0000u);
}
__device__ __forceinline__ float fexp2(float x) {   // raw v_exp_f32
    float r; asm("v_exp_f32 %0, %1" : "=v"(r) : "v"(x)); return r;
}
__device__ __forceinline__ float fmax3(float a, float b, float c) {
    float r; asm("v_max3_f32 %0, %1, %2, %3" : "=v"(r) : "v"(a), "v"(b), "v"(c));
    return r;
}

// ---------------- kernel 0: W pre-conversion to hi/lo A-fragments -----------
__global__ __launch_bounds__(256) void wprep_kernel(
    const float* __restrict__ Wq, const float* __restrict__ Wk,
    const float* __restrict__ Wv, const float* __restrict__ Wo,
    unsigned short* __restrict__ Wf, unsigned short* __restrict__ Wof)
{
    const int t = blockIdx.x * 256 + threadIdx.x;     // 65536 total
    if (t < 49152) {
        const int p = t >> 14, r = t & 16383;
        const int head = r >> 11, d = (r >> 4) & 127, kk = r & 15;
        const float wv = (p == 0 ? Wq : p == 1 ? Wk : Wv)[r];
        const unsigned short hi = f2bf(wv);
        const unsigned short lo = f2bf(wv - bf2f(hi));
        const int c = p * 8 + head, s = d >> 4, dd = d & 15;
        const int ch = dd >> 3, j = dd & 7;
        Wf[((c * 8 + s) * 64 + kk + 16 * ch) * 8 + j] = hi;
        Wf[((c * 8 + s) * 64 + kk + 16 * (2 + ch)) * 8 + j] = lo;
    } else {
        const int r = t - 49152;                       // Wo (8,16,128)
        const int head = r >> 11, v = (r >> 7) & 15, e = r & 127;
        const float wv = Wo[r];
        const unsigned short hi = f2bf(wv);
        const unsigned short lo = f2bf(wv - bf2f(hi));
        const int c = e >> 4, s = head, ch = v >> 3, j = v & 7;
        Wof[((c * 8 + s) * 64 + (e & 15) + 16 * ch) * 8 + j] = hi;
        Wof[((c * 8 + s) * 64 + (e & 15) + 16 * (2 + ch)) * 8 + j] = lo;
    }
}

// ---------------- kernel 1: QKV projection via MFMA (vectorized staging) ----
constexpr int GR = 32;
__global__ __launch_bounds__(256) void qkv_gemm(
    const float* __restrict__ h, const unsigned short* __restrict__ Wf,
    float* __restrict__ Q, unsigned short* __restrict__ KV)
{
    const int cg = blockIdx.x % 3;                    // 0=Q 1=K 2=V
    const int row0 = (blockIdx.x / 3) * GR;
    const int b = row0 >> 11, n0 = row0 & (N - 1);
    const int t = threadIdx.x, w = t >> 6, l = t & 63;
    __shared__ unsigned short hf[8][2][64][8];        // 16 KB

    #pragma unroll
    for (int pass = 0; pass < 4; ++pass) {
        const int rb = pass * 8 + (t >> 5);
        const int d0 = (t & 31) * 4;
        float4 hv = *(const float4*)&h[(size_t)(row0 + rb) * D + d0];
        const int s = d0 >> 4, ch = (d0 & 15) >> 3, j0 = d0 & 7;
        ushort4 hiv, lov;
        unsigned short* hp = (unsigned short*)&hiv;
        unsigned short* lp = (unsigned short*)&lov;
        #pragma unroll
        for (int i = 0; i < 4; ++i) {
            const float x = ((const float*)&hv)[i];
            const unsigned short hi = f2bf(x);
            hp[i] = hi;
            lp[i] = f2bf(x - bf2f(hi));
        }
        *(ushort4*)&hf[s][rb >> 4][(rb & 15) + 16 * ch][j0] = hiv;
        *(ushort4*)&hf[s][rb >> 4][(rb & 15) + 16 * (2 + ch)][j0] = lov;
    }
    __syncthreads();

    f32x4 acc[4];
    #pragma unroll
    for (int i = 0; i < 4; ++i) acc[i] = (f32x4){0.f, 0.f, 0.f, 0.f};

    const int cbase = cg * 8 + (w >> 1) * 4;
    bf16x8 afc[4], afn[4];
    #pragma unroll
    for (int ct = 0; ct < 4; ++ct)
        afc[ct] = *(const bf16x8*)&Wf[(((cbase + ct) * 8 + 0) * 64 + l) * 8];

    for (int s = 0; s < 8; ++s) {
        if (s + 1 < 8) {                              // prefetch next k-step
            #pragma unroll
            for (int ct = 0; ct < 4; ++ct)
                afn[ct] = *(const bf16x8*)&Wf[(((cbase + ct) * 8 + (s + 1)) * 64 + l) * 8];
        }
        bf16x8 b1 = *(const bf16x8*)&hf[s][w & 1][l][0];
        bf16x8 b2 = *(const bf16x8*)&hf[s][w & 1][l ^ 32][0];
        #pragma unroll
        for (int ct = 0; ct < 4; ++ct) {
            acc[ct] = __builtin_amdgcn_mfma_f32_16x16x32_bf16(afc[ct], b1, acc[ct], 0, 0, 0);
            acc[ct] = __builtin_amdgcn_mfma_f32_16x16x32_bf16(afc[ct], b2, acc[ct], 0, 0, 0);
        }
        #pragma unroll
        for (int ct = 0; ct < 4; ++ct) afc[ct] = afn[ct];
    }

    const int n = n0 + (w & 1) * 16 + (l & 15);
    const int rl = n & 127;
    const int kk0 = (l >> 4) * 4;
    #pragma unroll
    for (int ct = 0; ct < 4; ++ct) {
        const int head = (w >> 1) * 4 + ct;
        const int hb = head * B + b;
        if (cg == 0) {
            float4 o;
            o.x = acc[ct][0]; o.y = acc[ct][1]; o.z = acc[ct][2]; o.w = acc[ct][3];
            *(float4*)&Q[((size_t)hb * N + n) * DK + kk0] = o;
        } else {
            unsigned short* tb = KV + (size_t)hb * NTILES * TILE_SHORTS
                               + (size_t)(n >> 7) * TILE_SHORTS;
            if (cg == 1) {
                const int gs = kk0 >> 3, j0 = kk0 & 7;
                const int kb2 = rl >> 5, kap = rl & 31;
                const int sub = 2 * kb2 + ((kap >> 2) & 1);
                const int row16 = 4 * (kap >> 3) + (kap & 3);
                ushort4 sh, sl;
                unsigned short* shp = (unsigned short*)&sh;
                unsigned short* slp = (unsigned short*)&sl;
                #pragma unroll
                for (int r = 0; r < 4; ++r) {
                    const unsigned short hi = f2bf(acc[ct][r]);
                    shp[r] = hi;
                    slp[r] = f2bf(acc[ct][r] - bf2f(hi));
                }
                *(ushort4*)&tb[sub * 512 + (row16 + 16 * gs) * 8 + j0] = sh;
                *(ushort4*)&tb[sub * 512 + (row16 + 16 * (2 + gs)) * 8 + j0] = sl;
            } else {
                #pragma unroll
                for (int r = 0; r < 4; ++r) {
                    const int kk = kk0 + r;
                    tb[4096 + kk * 128 + ((rl >> 3) ^ (kk & 7)) * 8 + (rl & 7)]
                        = f2bf(acc[ct][r]);
                }
            }
        }
    }
}

// ---------------- kernel 2: flash attention (R16 + max3 trees) --------------
__global__ __launch_bounds__(512, 4) void attn_kernel(
    const float* __restrict__ Q, const unsigned short* __restrict__ KV,
    float* __restrict__ Hd)
{
    const int bid = blockIdx.x;                  // 0..511
    const int inner = bid >> 3;                  // 0..63
    const int hb = (bid & 7) * 4 + (inner >> 4); // XCD swizzle, bijective
    const int qt = inner & 15;
    const int t = threadIdx.x, w = t >> 6, l = t & 63;
    const int q16 = l & 15, g = l >> 4;
    const size_t qbase = (size_t)hb * N * DK;
    const char* kvb = (const char*)(KV + (size_t)hb * NTILES * TILE_SHORTS);

    __shared__ unsigned short smem[2][TILE_SHORTS];     // 2 x 12 KB

    const int qrow = qt * 128 + w * 16 + q16;
    bf16x8 qhi, qlo;
    {
        const float* qp = Q + qbase + (size_t)qrow * DK + (g & 1) * 8;
        float4 qa = *(const float4*)qp, qb = *(const float4*)(qp + 4);
        #pragma unroll
        for (int i = 0; i < 8; ++i) {
            const float x = (i < 4 ? ((const float*)&qa)[i] : ((const float*)&qb)[i - 4]) * QSCALE;
            const unsigned short hi = f2bf(x);
            qhi[i] = (short)hi;
            qlo[i] = (short)f2bf(x - bf2f(hi));
        }
    }
    const bf16x8 qf1 = (g < 2) ? qhi : qlo;
    const bf16x8 qf2 = (g < 2) ? qlo : qhi;

    union { unsigned u[4]; bf16x8 v; } ones;
    #pragma unroll
    for (int i = 0; i < 4; ++i) ones.u[i] = 0x3F803F80u;

    f32x4 oacc = {0.f, 0.f, 0.f, 0.f};
    f32x4 lacc = {0.f, 0.f, 0.f, 0.f};
    float m = 0.0f;                     // tile 0 normalizes to the true max

    // staging: 512 threads x 16B cover K (8192B); threads <256 cover V (4096B)
    uint4 s0 = *(const uint4*)(kvb + t * 16);
    uint4 s1;
    if (t < 256) s1 = *(const uint4*)(kvb + 8192 + t * 16);
    *(uint4*)((char*)&smem[0][0] + t * 16) = s0;
    if (t < 256) *(uint4*)((char*)&smem[0][0] + 8192 + t * 16) = s1;

    int cur = 0;
    for (int tile = 0; tile < NTILES; ++tile) {
        __syncthreads();
        if (tile + 1 < NTILES) {            // issue next-tile loads early (T14)
            const char* gt = kvb + (size_t)(tile + 1) * 12288;
            s0 = *(const uint4*)(gt + t * 16);
            if (t < 256) s1 = *(const uint4*)(gt + 8192 + t * 16);
        }
        const char* buf = (const char*)&smem[cur][0];

        f32x4 aA[4], aB[4];
        const f32x4 minit = {-m, -m, -m, -m};   // scores come out pre-shifted
        __builtin_amdgcn_s_setprio(1);
        #pragma unroll
        for (int kb = 0; kb < 4; ++kb) {
            bf16x8 kA = *(const bf16x8*)(buf + (2 * kb) * 1024 + l * 16);
            bf16x8 kB = *(const bf16x8*)(buf + (2 * kb + 1) * 1024 + l * 16);
            aA[kb] = __builtin_amdgcn_mfma_f32_16x16x32_bf16(kA, qf1, minit, 0, 0, 0);
            aA[kb] = __builtin_amdgcn_mfma_f32_16x16x32_bf16(kA, qf2, aA[kb], 0, 0, 0);
            aB[kb] = __builtin_amdgcn_mfma_f32_16x16x32_bf16(kB, qf1, minit, 0, 0, 0);
            aB[kb] = __builtin_amdgcn_mfma_f32_16x16x32_bf16(kB, qf2, aB[kb], 0, 0, 0);
        }
        __builtin_amdgcn_s_setprio(0);

        // in-lane max over 32 values via v_max3
        float tm = -3.0e38f;
        #pragma unroll
        for (int kb = 0; kb < 4; ++kb) {
            tm = fmax3(fmax3(aA[kb][0], aA[kb][1], aA[kb][2]),
                       fmax3(aA[kb][3], aB[kb][0], aB[kb][1]),
                       fmax3(aB[kb][2], aB[kb][3], tm));
        }
        // negligible-tile gate: contribution < 2^-30/key -> skip exp/pack/PV
        if (tile == 0 || !__all(tm <= -30.0f)) {
            if (tile == 0) {
                float d = fmaxf(tm, __shfl_xor(tm, 16));
                d = fmaxf(d, __shfl_xor(d, 32));
                m = d;                       // oacc/lacc are zero: no rescale
                #pragma unroll
                for (int kb = 0; kb < 4; ++kb) {
                    #pragma unroll
                    for (int i = 0; i < 4; ++i) { aA[kb][i] -= d; aB[kb][i] -= d; }
                }
            } else if (!__all(tm <= 8.0f)) { // rare: rescale + shift
                float d = fmaxf(tm, __shfl_xor(tm, 16));
                d = fmaxf(d, __shfl_xor(d, 32));
                const float dd = fmaxf(d, 0.f);
                const float sc = fexp2(-dd);
                m += dd;
                oacc *= sc;
                lacc *= sc;
                #pragma unroll
                for (int kb = 0; kb < 4; ++kb) {
                    #pragma unroll
                    for (int i = 0; i < 4; ++i) { aA[kb][i] -= dd; aB[kb][i] -= dd; }
                }
            }
            #pragma unroll
            for (int kb = 0; kb < 4; ++kb) {
                #pragma unroll
                for (int i = 0; i < 4; ++i) {
                    aA[kb][i] = fexp2(aA[kb][i]);    // no subtract: pre-shifted
                    aB[kb][i] = fexp2(aB[kb][i]);
                }
            }
            __builtin_amdgcn_s_setprio(1);
            #pragma unroll
            for (int kb = 0; kb < 4; ++kb) {
                union { unsigned u[4]; bf16x8 v; } pf;
                pf.u[0] = pack2(aA[kb][0], aA[kb][1]);
                pf.u[1] = pack2(aA[kb][2], aA[kb][3]);
                pf.u[2] = pack2(aB[kb][0], aB[kb][1]);
                pf.u[3] = pack2(aB[kb][2], aB[kb][3]);
                bf16x8 vf = *(const bf16x8*)(buf + 8192 + q16 * 256 + (((kb * 4 + g) ^ (q16 & 7)) * 16));
                oacc = __builtin_amdgcn_mfma_f32_16x16x32_bf16(vf, pf.v, oacc, 0, 0, 0);
                lacc = __builtin_amdgcn_mfma_f32_16x16x32_bf16(ones.v, pf.v, lacc, 0, 0, 0);
            }
            __builtin_amdgcn_s_setprio(0);
        }

        if (tile + 1 < NTILES) {
            char* nb = (char*)&smem[cur ^ 1][0];
            *(uint4*)(nb + t * 16) = s0;
            if (t < 256) *(uint4*)(nb + 8192 + t * 16) = s1;
        }
        cur ^= 1;
    }

    const float invl = 1.f / lacc[0];
    float4 o;
    o.x = oacc[0] * invl; o.y = oacc[1] * invl;
    o.z = oacc[2] * invl; o.w = oacc[3] * invl;
    *(float4*)(Hd + qbase + (size_t)qrow * DK + g * 4) = o;
}

// ---------------- kernel 3: output projection (vectorized staging) ----------
constexpr int OGR = 16;
__global__ __launch_bounds__(256) void out_gemm(
    const float* __restrict__ Hd, const unsigned short* __restrict__ Wof,
    float* __restrict__ out)
{
    const int row0 = blockIdx.x * OGR;
    const int b = row0 >> 11, n0 = row0 & (N - 1);
    const int t = threadIdx.x, w = t >> 6, l = t & 63;
    __shared__ unsigned short hf[8][64][8];           // 8 KB

    #pragma unroll
    for (int pass = 0; pass < 2; ++pass) {
        const int rb = pass * 8 + (t >> 5);           // 0..15
        const int d0 = (t & 31) * 4;                  // head = d0>>4
        float4 hv = *(const float4*)&Hd[((size_t)((d0 >> 4) * B + b) * N + (n0 + rb)) * DK + (d0 & 15)];
        const int s = d0 >> 4, ch = (d0 & 15) >> 3, j0 = d0 & 7;
        ushort4 hiv, lov;
        unsigned short* hp = (unsigned short*)&hiv;
        unsigned short* lp = (unsigned short*)&lov;
        #pragma unroll
        for (int i = 0; i < 4; ++i) {
            const float x = ((const float*)&hv)[i];
            const unsigned short hi = f2bf(x);
            hp[i] = hi;
            lp[i] = f2bf(x - bf2f(hi));
        }
        *(ushort4*)&hf[s][rb + 16 * ch][j0] = hiv;
        *(ushort4*)&hf[s][rb + 16 * (2 + ch)][j0] = lov;
    }
    __syncthreads();

    f32x4 acc[2];
    #pragma unroll
    for (int i = 0; i < 2; ++i) acc[i] = (f32x4){0.f, 0.f, 0.f, 0.f};

    bf16x8 afc[2], afn[2];
    #pragma unroll
    for (int ct = 0; ct < 2; ++ct)
        afc[ct] = *(const bf16x8*)&Wof[(((w * 2 + ct) * 8 + 0) * 64 + l) * 8];

    for (int s = 0; s < 8; ++s) {
        if (s + 1 < 8) {
            #pragma unroll
            for (int ct = 0; ct < 2; ++ct)
                afn[ct] = *(const bf16x8*)&Wof[(((w * 2 + ct) * 8 + (s + 1)) * 64 + l) * 8];
        }
        bf16x8 b1 = *(const bf16x8*)&hf[s][l][0];
        bf16x8 b2 = *(const bf16x8*)&hf[s][l ^ 32][0];
        #pragma unroll
        for (int ct = 0; ct < 2; ++ct) {
            acc[ct] = __builtin_amdgcn_mfma_f32_16x16x32_bf16(afc[ct], b1, acc[ct], 0, 0, 0);
            acc[ct] = __builtin_amdgcn_mfma_f32_16x16x32_bf16(afc[ct], b2, acc[ct], 0, 0, 0);
        }
        #pragma unroll
        for (int ct = 0; ct < 2; ++ct) afc[ct] = afn[ct];
    }

    const int n = row0 + (l & 15);
    #pragma unroll
    for (int ct = 0; ct < 2; ++ct) {
        const int c = w * 2 + ct;
        float4 o;
        o.x = acc[ct][0]; o.y = acc[ct][1]; o.z = acc[ct][2]; o.w = acc[ct][3];
        *(float4*)&out[(size_t)n * D + c * 16 + (l >> 4) * 4] = o;
    }
}

extern "C" void kernel_launch(void* const* d_in, const int* in_sizes, int n_in,
                              void* d_out, int out_size, void* d_ws, size_t ws_size,
                              hipStream_t stream) {
    const float* h  = (const float*)d_in[0];
    const float* Wq = (const float*)d_in[1];
    const float* Wk = (const float*)d_in[2];
    const float* Wv = (const float*)d_in[3];
    const float* Wo = (const float*)d_in[4];
    float* out = (float*)d_out;

    char* ws = (char*)d_ws;
    float* Q = (float*)ws;                                   // 4 MB (heads alias)
    unsigned short* KV  = (unsigned short*)(ws + (size_t)4 * 1024 * 1024);  // 6 MB
    unsigned short* Wf  = (unsigned short*)(ws + (size_t)10 * 1024 * 1024); // 192 KB
    unsigned short* Wof = (unsigned short*)(ws + (size_t)10 * 1024 * 1024 + 196608); // 64 KB

    wprep_kernel<<<256, 256, 0, stream>>>(Wq, Wk, Wv, Wo, Wf, Wof);
    qkv_gemm<<<(B * N / GR) * 3, 256, 0, stream>>>(h, Wf, Q, KV);
    attn_kernel<<<NH * B * 16, 512, 0, stream>>>(Q, KV, Q);
    out_gemm<<<B * N / OGR, 256, 0, stream>>>(Q, Wof, out);
}

// Round 23
// 54.447 us; speedup vs baseline: 1.0296x; 1.0296x over previous
//
#include <hip/hip_runtime.h>

typedef __attribute__((ext_vector_type(4))) float f32x4;
typedef __attribute__((ext_vector_type(8))) short bf16x8;

constexpr int NH = 8, D = 128, DK = 16, B = 4, N = 2048;
constexpr int KTILE = 128;
constexpr int NTILES = N / KTILE;       // 16 key-tiles of 128
constexpr int TILE_SHORTS = 6144;       // 12288 B: 8192 B Khl frag + 4096 B Vt swz
constexpr float QSCALE = 0.36067376022224085f;   // 0.25 * log2(e)

__device__ __forceinline__ unsigned short f2bf(float f) {
    union { float f; unsigned u; } v; v.f = f;
    return (unsigned short)((v.u + 0x7fffu + ((v.u >> 16) & 1u)) >> 16);
}
__device__ __forceinline__ float bf2f(unsigned short h) {
    union { unsigned u; float f; } v; v.u = ((unsigned)h) << 16; return v.f;
}
__device__ __forceinline__ unsigned pack2(float a, float b) {   // bf16 trunc pair
    union { float f; unsigned u; } x, y; x.f = a; y.f = b;
    return (x.u >> 16) | (y.u & 0xFFFF0000u);
}
__device__ __forceinline__ float fexp2(float x) {   // raw v_exp_f32
    float r; asm("v_exp_f32 %0, %1" : "=v"(r) : "v"(x)); return r;
}
__device__ __forceinline__ float fmax3(float a, float b, float c) {
    float r; asm("v_max3_f32 %0, %1, %2, %3" : "=v"(r) : "v"(a), "v"(b), "v"(c));
    return r;
}

// ---------------- kernel 0: W pre-conversion to hi/lo A-fragments -----------
__global__ __launch_bounds__(256) void wprep_kernel(
    const float* __restrict__ Wq, const float* __restrict__ Wk,
    const float* __restrict__ Wv, const float* __restrict__ Wo,
    unsigned short* __restrict__ Wf, unsigned short* __restrict__ Wof)
{
    const int t = blockIdx.x * 256 + threadIdx.x;     // 65536 total
    if (t < 49152) {
        const int p = t >> 14, r = t & 16383;
        const int head = r >> 11, d = (r >> 4) & 127, kk = r & 15;
        const float wv = (p == 0 ? Wq : p == 1 ? Wk : Wv)[r];
        const unsigned short hi = f2bf(wv);
        const unsigned short lo = f2bf(wv - bf2f(hi));
        const int c = p * 8 + head, s = d >> 4, dd = d & 15;
        const int ch = dd >> 3, j = dd & 7;
        Wf[((c * 8 + s) * 64 + kk + 16 * ch) * 8 + j] = hi;
        Wf[((c * 8 + s) * 64 + kk + 16 * (2 + ch)) * 8 + j] = lo;
    } else {
        const int r = t - 49152;                       // Wo (8,16,128)
        const int head = r >> 11, v = (r >> 7) & 15, e = r & 127;
        const float wv = Wo[r];
        const unsigned short hi = f2bf(wv);
        const unsigned short lo = f2bf(wv - bf2f(hi));
        const int c = e >> 4, s = head, ch = v >> 3, j = v & 7;
        Wof[((c * 8 + s) * 64 + (e & 15) + 16 * ch) * 8 + j] = hi;
        Wof[((c * 8 + s) * 64 + (e & 15) + 16 * (2 + ch)) * 8 + j] = lo;
    }
}

// ---------------- kernel 1: QKV projection via MFMA (48 KB LDS-staged Wf) ---
// Grid = 256*6: cg = Q/K/V, hg = head-group of 4. Wf slice for 4 head-cols is
// 16384 shorts = 32 KB (+16 KB hf = 48 KB < 64 KB static limit). af reads are
// ds_read_b128 instead of ~250cy L2 hits. Each wave: 2 col-tiles.
constexpr int GR = 32;
__global__ __launch_bounds__(256) void qkv_gemm(
    const float* __restrict__ h, const unsigned short* __restrict__ Wf,
    float* __restrict__ Q, unsigned short* __restrict__ KV)
{
    const int cg6 = blockIdx.x % 6;
    const int cg = cg6 >> 1;                          // 0=Q 1=K 2=V
    const int hg = cg6 & 1;                           // heads hg*4..hg*4+3
    const int row0 = (blockIdx.x / 6) * GR;
    const int b = row0 >> 11, n0 = row0 & (N - 1);
    const int t = threadIdx.x, w = t >> 6, l = t & 63;
    __shared__ unsigned short hf[8][2][64][8];        // 16 KB
    __shared__ unsigned short wfl[4][8][64][8];       // 32 KB [c4][s][row][j]

    // stage Wf slice: 16384 shorts = 2048 uint4; 8 per thread (linear)
    {
        const unsigned short* wsrc = Wf + ((size_t)cg * 8 + hg * 4) * 4096;
        unsigned short* wdst = (unsigned short*)wfl;
        #pragma unroll
        for (int i = 0; i < 8; ++i) {
            const int idx = (t + i * 256) * 8;
            *(uint4*)&wdst[idx] = *(const uint4*)&wsrc[idx];
        }
    }
    #pragma unroll
    for (int pass = 0; pass < 4; ++pass) {
        const int rb = pass * 8 + (t >> 5);
        const int d0 = (t & 31) * 4;
        float4 hv = *(const float4*)&h[(size_t)(row0 + rb) * D + d0];
        const int s = d0 >> 4, ch = (d0 & 15) >> 3, j0 = d0 & 7;
        ushort4 hiv, lov;
        unsigned short* hp = (unsigned short*)&hiv;
        unsigned short* lp = (unsigned short*)&lov;
        #pragma unroll
        for (int i = 0; i < 4; ++i) {
            const float x = ((const float*)&hv)[i];
            const unsigned short hi = f2bf(x);
            hp[i] = hi;
            lp[i] = f2bf(x - bf2f(hi));
        }
        *(ushort4*)&hf[s][rb >> 4][(rb & 15) + 16 * ch][j0] = hiv;
        *(ushort4*)&hf[s][rb >> 4][(rb & 15) + 16 * (2 + ch)][j0] = lov;
    }
    __syncthreads();

    f32x4 acc[2];
    #pragma unroll
    for (int i = 0; i < 2; ++i) acc[i] = (f32x4){0.f, 0.f, 0.f, 0.f};

    for (int s = 0; s < 8; ++s) {
        bf16x8 b1 = *(const bf16x8*)&hf[s][w & 1][l][0];
        bf16x8 b2 = *(const bf16x8*)&hf[s][w & 1][l ^ 32][0];
        #pragma unroll
        for (int ct = 0; ct < 2; ++ct) {
            const int c4 = (w >> 1) * 2 + ct;         // 0..3
            bf16x8 af = *(const bf16x8*)&wfl[c4][s][l][0];
            acc[ct] = __builtin_amdgcn_mfma_f32_16x16x32_bf16(af, b1, acc[ct], 0, 0, 0);
            acc[ct] = __builtin_amdgcn_mfma_f32_16x16x32_bf16(af, b2, acc[ct], 0, 0, 0);
        }
    }

    const int n = n0 + (w & 1) * 16 + (l & 15);
    const int rl = n & 127;
    const int kk0 = (l >> 4) * 4;
    #pragma unroll
    for (int ct = 0; ct < 2; ++ct) {
        const int head = hg * 4 + (w >> 1) * 2 + ct;
        const int hb = head * B + b;
        if (cg == 0) {
            float4 o;
            o.x = acc[ct][0]; o.y = acc[ct][1]; o.z = acc[ct][2]; o.w = acc[ct][3];
            *(float4*)&Q[((size_t)hb * N + n) * DK + kk0] = o;
        } else {
            unsigned short* tb = KV + (size_t)hb * NTILES * TILE_SHORTS
                               + (size_t)(n >> 7) * TILE_SHORTS;
            if (cg == 1) {
                const int gs = kk0 >> 3, j0 = kk0 & 7;
                const int kb2 = rl >> 5, kap = rl & 31;
                const int sub = 2 * kb2 + ((kap >> 2) & 1);
                const int row16 = 4 * (kap >> 3) + (kap & 3);
                ushort4 sh, sl;
                unsigned short* shp = (unsigned short*)&sh;
                unsigned short* slp = (unsigned short*)&sl;
                #pragma unroll
                for (int r = 0; r < 4; ++r) {
                    const unsigned short hi = f2bf(acc[ct][r]);
                    shp[r] = hi;
                    slp[r] = f2bf(acc[ct][r] - bf2f(hi));
                }
                *(ushort4*)&tb[sub * 512 + (row16 + 16 * gs) * 8 + j0] = sh;
                *(ushort4*)&tb[sub * 512 + (row16 + 16 * (2 + gs)) * 8 + j0] = sl;
            } else {
                #pragma unroll
                for (int r = 0; r < 4; ++r) {
                    const int kk = kk0 + r;
                    tb[4096 + kk * 128 + ((rl >> 3) ^ (kk & 7)) * 8 + (rl & 7)]
                        = f2bf(acc[ct][r]);
                }
            }
        }
    }
}

// ---------------- kernel 2: flash attention (R21 exact) ---------------------
__global__ __launch_bounds__(512, 4) void attn_kernel(
    const float* __restrict__ Q, const unsigned short* __restrict__ KV,
    float* __restrict__ Hd)
{
    const int bid = blockIdx.x;                  // 0..511
    const int inner = bid >> 3;                  // 0..63
    const int hb = (bid & 7) * 4 + (inner >> 4); // XCD swizzle, bijective
    const int qt = inner & 15;
    const int t = threadIdx.x, w = t >> 6, l = t & 63;
    const int q16 = l & 15, g = l >> 4;
    const size_t qbase = (size_t)hb * N * DK;
    const char* kvb = (const char*)(KV + (size_t)hb * NTILES * TILE_SHORTS);

    __shared__ unsigned short smem[2][TILE_SHORTS];     // 2 x 12 KB

    const int qrow = qt * 128 + w * 16 + q16;
    bf16x8 qhi, qlo;
    {
        const float* qp = Q + qbase + (size_t)qrow * DK + (g & 1) * 8;
        float4 qa = *(const float4*)qp, qb = *(const float4*)(qp + 4);
        #pragma unroll
        for (int i = 0; i < 8; ++i) {
            const float x = (i < 4 ? ((const float*)&qa)[i] : ((const float*)&qb)[i - 4]) * QSCALE;
            const unsigned short hi = f2bf(x);
            qhi[i] = (short)hi;
            qlo[i] = (short)f2bf(x - bf2f(hi));
        }
    }
    const bf16x8 qf1 = (g < 2) ? qhi : qlo;
    const bf16x8 qf2 = (g < 2) ? qlo : qhi;

    union { unsigned u[4]; bf16x8 v; } ones;
    #pragma unroll
    for (int i = 0; i < 4; ++i) ones.u[i] = 0x3F803F80u;

    f32x4 oacc = {0.f, 0.f, 0.f, 0.f};
    f32x4 lacc = {0.f, 0.f, 0.f, 0.f};
    float m = 0.0f;                     // tile 0 normalizes to the true max

    // staging: 512 threads x 16B cover K (8192B); threads <256 cover V (4096B)
    uint4 s0 = *(const uint4*)(kvb + t * 16);
    uint4 s1;
    if (t < 256) s1 = *(const uint4*)(kvb + 8192 + t * 16);
    *(uint4*)((char*)&smem[0][0] + t * 16) = s0;
    if (t < 256) *(uint4*)((char*)&smem[0][0] + 8192 + t * 16) = s1;

    int cur = 0;
    for (int tile = 0; tile < NTILES; ++tile) {
        __syncthreads();
        if (tile + 1 < NTILES) {            // issue next-tile loads early (T14)
            const char* gt = kvb + (size_t)(tile + 1) * 12288;
            s0 = *(const uint4*)(gt + t * 16);
            if (t < 256) s1 = *(const uint4*)(gt + 8192 + t * 16);
        }
        const char* buf = (const char*)&smem[cur][0];

        f32x4 aA[4], aB[4];
        const f32x4 minit = {-m, -m, -m, -m};   // scores come out pre-shifted
        __builtin_amdgcn_s_setprio(1);
        #pragma unroll
        for (int kb = 0; kb < 4; ++kb) {
            bf16x8 kA = *(const bf16x8*)(buf + (2 * kb) * 1024 + l * 16);
            bf16x8 kB = *(const bf16x8*)(buf + (2 * kb + 1) * 1024 + l * 16);
            aA[kb] = __builtin_amdgcn_mfma_f32_16x16x32_bf16(kA, qf1, minit, 0, 0, 0);
            aA[kb] = __builtin_amdgcn_mfma_f32_16x16x32_bf16(kA, qf2, aA[kb], 0, 0, 0);
            aB[kb] = __builtin_amdgcn_mfma_f32_16x16x32_bf16(kB, qf1, minit, 0, 0, 0);
            aB[kb] = __builtin_amdgcn_mfma_f32_16x16x32_bf16(kB, qf2, aB[kb], 0, 0, 0);
        }
        __builtin_amdgcn_s_setprio(0);

        // in-lane max over 32 values via v_max3
        float tm = -3.0e38f;
        #pragma unroll
        for (int kb = 0; kb < 4; ++kb) {
            tm = fmax3(fmax3(aA[kb][0], aA[kb][1], aA[kb][2]),
                       fmax3(aA[kb][3], aB[kb][0], aB[kb][1]),
                       fmax3(aB[kb][2], aB[kb][3], tm));
        }
        // negligible-tile gate: contribution < 2^-30/key -> skip exp/pack/PV
        if (tile == 0 || !__all(tm <= -30.0f)) {
            if (tile == 0) {
                float d = fmaxf(tm, __shfl_xor(tm, 16));
                d = fmaxf(d, __shfl_xor(d, 32));
                m = d;                       // oacc/lacc are zero: no rescale
                #pragma unroll
                for (int kb = 0; kb < 4; ++kb) {
                    #pragma unroll
                    for (int i = 0; i < 4; ++i) { aA[kb][i] -= d; aB[kb][i] -= d; }
                }
            } else if (!__all(tm <= 8.0f)) { // rare: rescale + shift
                float d = fmaxf(tm, __shfl_xor(tm, 16));
                d = fmaxf(d, __shfl_xor(d, 32));
                const float dd = fmaxf(d, 0.f);
                const float sc = fexp2(-dd);
                m += dd;
                oacc *= sc;
                lacc *= sc;
                #pragma unroll
                for (int kb = 0; kb < 4; ++kb) {
                    #pragma unroll
                    for (int i = 0; i < 4; ++i) { aA[kb][i] -= dd; aB[kb][i] -= dd; }
                }
            }
            #pragma unroll
            for (int kb = 0; kb < 4; ++kb) {
                #pragma unroll
                for (int i = 0; i < 4; ++i) {
                    aA[kb][i] = fexp2(aA[kb][i]);    // no subtract: pre-shifted
                    aB[kb][i] = fexp2(aB[kb][i]);
                }
            }
            __builtin_amdgcn_s_setprio(1);
            #pragma unroll
            for (int kb = 0; kb < 4; ++kb) {
                union { unsigned u[4]; bf16x8 v; } pf;
                pf.u[0] = pack2(aA[kb][0], aA[kb][1]);
                pf.u[1] = pack2(aA[kb][2], aA[kb][3]);
                pf.u[2] = pack2(aB[kb][0], aB[kb][1]);
                pf.u[3] = pack2(aB[kb][2], aB[kb][3]);
                bf16x8 vf = *(const bf16x8*)(buf + 8192 + q16 * 256 + (((kb * 4 + g) ^ (q16 & 7)) * 16));
                oacc = __builtin_amdgcn_mfma_f32_16x16x32_bf16(vf, pf.v, oacc, 0, 0, 0);
                lacc = __builtin_amdgcn_mfma_f32_16x16x32_bf16(ones.v, pf.v, lacc, 0, 0, 0);
            }
            __builtin_amdgcn_s_setprio(0);
        }

        if (tile + 1 < NTILES) {
            char* nb = (char*)&smem[cur ^ 1][0];
            *(uint4*)(nb + t * 16) = s0;
            if (t < 256) *(uint4*)(nb + 8192 + t * 16) = s1;
        }
        cur ^= 1;
    }

    const float invl = 1.f / lacc[0];
    float4 o;
    o.x = oacc[0] * invl; o.y = oacc[1] * invl;
    o.z = oacc[2] * invl; o.w = oacc[3] * invl;
    *(float4*)(Hd + qbase + (size_t)qrow * DK + g * 4) = o;
}

// ---------------- kernel 3: output projection (R21 exact) -------------------
constexpr int OGR = 16;
__global__ __launch_bounds__(256) void out_gemm(
    const float* __restrict__ Hd, const unsigned short* __restrict__ Wof,
    float* __restrict__ out)
{
    const int row0 = blockIdx.x * OGR;
    const int b = row0 >> 11, n0 = row0 & (N - 1);
    const int t = threadIdx.x, w = t >> 6, l = t & 63;
    __shared__ unsigned short hf[8][64][8];           // 8 KB

    #pragma unroll
    for (int pass = 0; pass < 2; ++pass) {
        const int rb = pass * 8 + (t >> 5);           // 0..15
        const int d0 = (t & 31) * 4;                  // head = d0>>4
        float4 hv = *(const float4*)&Hd[((size_t)((d0 >> 4) * B + b) * N + (n0 + rb)) * DK + (d0 & 15)];
        const int s = d0 >> 4, ch = (d0 & 15) >> 3, j0 = d0 & 7;
        ushort4 hiv, lov;
        unsigned short* hp = (unsigned short*)&hiv;
        unsigned short* lp = (unsigned short*)&lov;
        #pragma unroll
        for (int i = 0; i < 4; ++i) {
            const float x = ((const float*)&hv)[i];
            const unsigned short hi = f2bf(x);
            hp[i] = hi;
            lp[i] = f2bf(x - bf2f(hi));
        }
        *(ushort4*)&hf[s][rb + 16 * ch][j0] = hiv;
        *(ushort4*)&hf[s][rb + 16 * (2 + ch)][j0] = lov;
    }
    __syncthreads();

    f32x4 acc[2];
    #pragma unroll
    for (int i = 0; i < 2; ++i) acc[i] = (f32x4){0.f, 0.f, 0.f, 0.f};

    bf16x8 afc[2], afn[2];
    #pragma unroll
    for (int ct = 0; ct < 2; ++ct)
        afc[ct] = *(const bf16x8*)&Wof[(((w * 2 + ct) * 8 + 0) * 64 + l) * 8];

    for (int s = 0; s < 8; ++s) {
        if (s + 1 < 8) {
            #pragma unroll
            for (int ct = 0; ct < 2; ++ct)
                afn[ct] = *(const bf16x8*)&Wof[(((w * 2 + ct) * 8 + (s + 1)) * 64 + l) * 8];
        }
        bf16x8 b1 = *(const bf16x8*)&hf[s][l][0];
        bf16x8 b2 = *(const bf16x8*)&hf[s][l ^ 32][0];
        #pragma unroll
        for (int ct = 0; ct < 2; ++ct) {
            acc[ct] = __builtin_amdgcn_mfma_f32_16x16x32_bf16(afc[ct], b1, acc[ct], 0, 0, 0);
            acc[ct] = __builtin_amdgcn_mfma_f32_16x16x32_bf16(afc[ct], b2, acc[ct], 0, 0, 0);
        }
        #pragma unroll
        for (int ct = 0; ct < 2; ++ct) afc[ct] = afn[ct];
    }

    const int n = row0 + (l & 15);
    #pragma unroll
    for (int ct = 0; ct < 2; ++ct) {
        const int c = w * 2 + ct;
        float4 o;
        o.x = acc[ct][0]; o.y = acc[ct][1]; o.z = acc[ct][2]; o.w = acc[ct][3];
        *(float4*)&out[(size_t)n * D + c * 16 + (l >> 4) * 4] = o;
    }
}

extern "C" void kernel_launch(void* const* d_in, const int* in_sizes, int n_in,
                              void* d_out, int out_size, void* d_ws, size_t ws_size,
                              hipStream_t stream) {
    const float* h  = (const float*)d_in[0];
    const float* Wq = (const float*)d_in[1];
    const float* Wk = (const float*)d_in[2];
    const float* Wv = (const float*)d_in[3];
    const float* Wo = (const float*)d_in[4];
    float* out = (float*)d_out;

    char* ws = (char*)d_ws;
    float* Q = (float*)ws;                                   // 4 MB (heads alias)
    unsigned short* KV  = (unsigned short*)(ws + (size_t)4 * 1024 * 1024);  // 6 MB
    unsigned short* Wf  = (unsigned short*)(ws + (size_t)10 * 1024 * 1024); // 192 KB
    unsigned short* Wof = (unsigned short*)(ws + (size_t)10 * 1024 * 1024 + 196608); // 64 KB

    wprep_kernel<<<256, 256, 0, stream>>>(Wq, Wk, Wv, Wo, Wf, Wof);
    qkv_gemm<<<(B * N / GR) * 6, 256, 0, stream>>>(h, Wf, Q, KV);
    attn_kernel<<<NH * B * 16, 512, 0, stream>>>(Q, KV, Q);
    out_gemm<<<B * N / OGR, 256, 0, stream>>>(Q, Wof, out);
}